// Round 5
// baseline (20672.539 us; speedup 1.0000x reference)
//
#include <hip/hip_runtime.h>
#include <math.h>

#define NB   4096
#define NIN  768
#define NLAT 24576
#define K2   1536   // [Ah|Al] x [Bh|Bh]
#define KT2  24     // K2/64

// f32 fallback GEMM tiling
#define BM 128
#define BN 128
#define BK 16
#define LDT 132

#define CAND_CAP 160
#define BAND_CAP 160
#define MAIN_CAP 64
#define AUX_CAP  1024
#define SELT     1024
#define EPT      24     // elements per thread = NLAT/SELT
#define GRP      6      // float4 groups per thread

typedef __bf16 bf16x8 __attribute__((ext_vector_type(8)));
typedef float  f32x4  __attribute__((ext_vector_type(4)));

__device__ __forceinline__ unsigned fkey(float f) {
  unsigned u = __float_as_uint(f);
  return u ^ ((unsigned)((int)u >> 31) | 0x80000000u);  // monotone total order
}
__device__ __forceinline__ float keyinv(unsigned u) {
  unsigned s = (u & 0x80000000u) ? (u ^ 0x80000000u) : ~u;
  return __uint_as_float(s);
}

#define GLOAD16(g, l) __builtin_amdgcn_global_load_lds( \
    (const __attribute__((address_space(1))) unsigned int*)(g), \
    (__attribute__((address_space(3))) unsigned int*)(l), 16, 0, 0)

// ---------------- dead bitset: bit j = (miss[j] >= 1) ----------------
__global__ __launch_bounds__(256) void k_deadbits(const int* __restrict__ miss,
                                                  unsigned* __restrict__ bits) {
  int j = blockIdx.x * 256 + threadIdx.x;
  unsigned long long b = __ballot(miss[j] >= 1);
  if ((threadIdx.x & 63) == 0) {
    int w = j >> 5;
    bits[w] = (unsigned)b;
    bits[w + 1] = (unsigned)(b >> 32);
  }
}

// ---------------- W_dec [NIN][NLAT] -> Wt [NLAT][NIN] (bf16) ----------------
__global__ __launch_bounds__(256) void k_transpose(const float* __restrict__ src,
                                                   __bf16* __restrict__ dst) {
  __shared__ float tile[32][33];
  int bx = blockIdx.x * 32;  // NLAT
  int by = blockIdx.y * 32;  // NIN
  int tx = threadIdx.x, ty = threadIdx.y;
  for (int i = ty; i < 32; i += 8)
    tile[i][tx] = src[(size_t)(by + i) * NLAT + bx + tx];
  __syncthreads();
  for (int i = ty; i < 32; i += 8)
    dst[(size_t)(bx + i) * NIN + by + tx] = (__bf16)tile[tx][i];
}

// ---- pack (x-b) into A2 tiles [mt][kt][128][64], pre-swizzled LDS image ----
__global__ __launch_bounds__(256) void k_pack_a(const float* __restrict__ x,
    const float* __restrict__ bvec, __bf16* __restrict__ A2) {
  const int mt = blockIdx.x, kt = blockIdx.y, t = threadIdx.x;
  __bf16* out = A2 + (((size_t)mt * KT2 + kt) << 13);
#pragma unroll
  for (int i = 0; i < 32; ++i) {
    int idx = i * 256 + t;
    int r = idx >> 6, c2 = idx & 63;
    int kk = c2 ^ ((r & 7) << 3);
    int kg = kt * 64 + kk;
    int k = kg >= 768 ? kg - 768 : kg;
    bool lo = (kg >= 768);                            // A = [Ah | Al]
    float v = x[(size_t)(mt * 128 + r) * NIN + k] - bvec[k];
    __bf16 h = (__bf16)v;
    out[idx] = lo ? (__bf16)(v - (float)h) : h;
  }
}

__global__ __launch_bounds__(256) void k_pack_b(const float* __restrict__ We,
    __bf16* __restrict__ B2) {
  const int nt = blockIdx.x, kt = blockIdx.y, t = threadIdx.x;
  __bf16* out = B2 + (((size_t)nt * KT2 + kt) << 13);
#pragma unroll
  for (int i = 0; i < 32; ++i) {
    int idx = i * 256 + t;
    int r = idx >> 6, c2 = idx & 63;
    int kk = c2 ^ ((r & 7) << 3);
    int kg = kt * 64 + kk;
    int k = kg >= 768 ? kg - 768 : kg;                // B = [Bh | Bh]
    float v = We[(size_t)(nt * 128 + r) * NIN + k];
    out[idx] = (__bf16)v;
  }
}

// ---------------- bf16 MFMA GEMM: apre = A2 @ B2^T + be ----------------
__global__ __launch_bounds__(256) void k_gemm_bf16(
    const __bf16* __restrict__ A2, const __bf16* __restrict__ B2,
    const float* __restrict__ be, float* __restrict__ apre) {
  __shared__ char sA[16384];
  __shared__ char sB[16384];
  const int t = threadIdx.x;
  const int lane = t & 63, wave = t >> 6;
  const int mt = blockIdx.x, nt = blockIdx.y;
  const int wm = wave >> 1, wn = wave & 1;

  int aoff[4][2], boff[4][2];
#pragma unroll
  for (int f = 0; f < 4; ++f) {
    int ra = wm * 64 + f * 16 + (lane & 15);
    int rb = wn * 64 + f * 16 + (lane & 15);
#pragma unroll
    for (int kk = 0; kk < 2; ++kk) {
      int c = kk * 64 + (lane >> 4) * 16;
      aoff[f][kk] = ra * 128 + (c ^ ((ra & 7) << 4));
      boff[f][kk] = rb * 128 + (c ^ ((rb & 7) << 4));
    }
  }
  f32x4 acc[4][4] = {};
  const char* gA = (const char*)(A2 + (((size_t)mt * KT2) << 13));
  const char* gB = (const char*)(B2 + (((size_t)nt * KT2) << 13));
  for (int kt = 0; kt < KT2; ++kt) {
    const char* tA = gA + ((size_t)kt << 14);
    const char* tB = gB + ((size_t)kt << 14);
#pragma unroll
    for (int i = 0; i < 4; ++i) {
      int chunk = (i * 4 + wave) * 1024;
      GLOAD16(tA + chunk + lane * 16, sA + chunk);
      GLOAD16(tB + chunk + lane * 16, sB + chunk);
    }
    __syncthreads();
#pragma unroll
    for (int kk = 0; kk < 2; ++kk) {
      bf16x8 a[4], b[4];
#pragma unroll
      for (int f = 0; f < 4; ++f) {
        a[f] = *(const bf16x8*)(sA + aoff[f][kk]);
        b[f] = *(const bf16x8*)(sB + boff[f][kk]);
      }
#pragma unroll
      for (int mi = 0; mi < 4; ++mi)
#pragma unroll
        for (int ni = 0; ni < 4; ++ni)
          acc[mi][ni] = __builtin_amdgcn_mfma_f32_16x16x32_bf16(a[mi], b[ni], acc[mi][ni], 0, 0, 0);
    }
    __syncthreads();
  }
  const int m0 = mt * 128 + wm * 64, n0 = nt * 128 + wn * 64;
#pragma unroll
  for (int ni = 0; ni < 4; ++ni) {
    int n = n0 + ni * 16 + (lane & 15);
    float bb = be[n];
#pragma unroll
    for (int mi = 0; mi < 4; ++mi) {
      int mbase = m0 + mi * 16 + (lane >> 4) * 4;
#pragma unroll
      for (int q = 0; q < 4; ++q)
        apre[(size_t)(mbase + q) * NLAT + n] = acc[mi][ni][q] + bb;
    }
  }
}

// ---------------- f32 fallback GEMM ----------------
__global__ __launch_bounds__(256) void k_encgemm_f32(
    const float* __restrict__ x, const float* __restrict__ bvec,
    const float* __restrict__ We, const float* __restrict__ be,
    float* __restrict__ apre) {
  __shared__ float As[BK][LDT];
  __shared__ float Bs[BK][LDT];
  const int t = threadIdx.x;
  const int m0 = blockIdx.x * BM;
  const int n0 = blockIdx.y * BN;
  const int lane = t & 63, wave = t >> 6;
  const int cn = ((wave & 1) * 8 + (lane & 7)) * 8;
  const int cm = ((wave >> 1) * 8 + (lane >> 3)) * 8;
  float acc[8][8] = {};
  const float* xb = x + (size_t)m0 * NIN;
  const float* wb = We + (size_t)n0 * NIN;
  for (int k0 = 0; k0 < NIN; k0 += BK) {
#pragma unroll
    for (int i = 0; i < 2; ++i) {
      int e = t + i * 256;
      int row = e >> 2, q = e & 3;
      float4 bv = *(const float4*)(bvec + k0 + q * 4);
      float4 av = *(const float4*)(xb + (size_t)row * NIN + k0 + q * 4);
      av.x -= bv.x; av.y -= bv.y; av.z -= bv.z; av.w -= bv.w;
      As[q * 4 + 0][row] = av.x; As[q * 4 + 1][row] = av.y;
      As[q * 4 + 2][row] = av.z; As[q * 4 + 3][row] = av.w;
      float4 wv = *(const float4*)(wb + (size_t)row * NIN + k0 + q * 4);
      Bs[q * 4 + 0][row] = wv.x; Bs[q * 4 + 1][row] = wv.y;
      Bs[q * 4 + 2][row] = wv.z; Bs[q * 4 + 3][row] = wv.w;
    }
    __syncthreads();
#pragma unroll
    for (int kk = 0; kk < BK; ++kk) {
      float a0[8], b0[8];
      *(float4*)&a0[0] = *(const float4*)&As[kk][cm];
      *(float4*)&a0[4] = *(const float4*)&As[kk][cm + 4];
      *(float4*)&b0[0] = *(const float4*)&Bs[kk][cn];
      *(float4*)&b0[4] = *(const float4*)&Bs[kk][cn + 4];
#pragma unroll
      for (int i = 0; i < 8; ++i)
#pragma unroll
        for (int j = 0; j < 8; ++j)
          acc[i][j] = fmaf(a0[i], b0[j], acc[i][j]);
    }
    __syncthreads();
  }
  float bb[8];
  *(float4*)&bb[0] = *(const float4*)(be + n0 + cn);
  *(float4*)&bb[4] = *(const float4*)(be + n0 + cn + 4);
#pragma unroll
  for (int i = 0; i < 8; ++i) {
    float4 v0 = make_float4(acc[i][0] + bb[0], acc[i][1] + bb[1],
                            acc[i][2] + bb[2], acc[i][3] + bb[3]);
    float4 v1 = make_float4(acc[i][4] + bb[4], acc[i][5] + bb[5],
                            acc[i][6] + bb[6], acc[i][7] + bb[7]);
    float* orow = apre + (size_t)(m0 + cm + i) * NLAT + n0 + cn;
    *(float4*)orow = v0;
    *(float4*)(orow + 4) = v1;
  }
}

// ------------- per-row: 1024-thread register-resident bisection top-k ----
// apre and mask alias — no __restrict__ on either; each block owns its row.
__global__ __launch_bounds__(SELT) void k_select4(
    const float* apre, const float* __restrict__ x,
    const float* __restrict__ bvec, const float* __restrict__ We,
    const float* __restrict__ be, const unsigned* __restrict__ dbits,
    const int* __restrict__ kptr, const int* __restrict__ akptr,
    float* __restrict__ alpha, float* mask,
    float* __restrict__ xhat, float* __restrict__ auxo,
    const __bf16* __restrict__ Wt, const float* __restrict__ Wd) {
  const int t = threadIdx.x;
  const int r = blockIdx.x;
  const int lane = t & 63, wave = t >> 6;   // 16 waves

  __shared__ int wred[2][48];
  __shared__ unsigned wredu[2][16];
  __shared__ int ctrl[8];
  __shared__ unsigned candK[CAND_CAP];
  __shared__ int candI[CAND_CAP];
  __shared__ int bandI[BAND_CAP];
  __shared__ double bandV[BAND_CAP];
  __shared__ unsigned char bandSel[BAND_CAP];
  __shared__ int mIdx[MAIN_CAP];
  __shared__ float mVal[MAIN_CAP];
  __shared__ int aIdx[AUX_CAP];
  __shared__ float aVal[AUX_CAP];

  // ---- load row as sort keys (24 regs) + dead bits (1 reg) ----
  unsigned key[EPT];
  const float4* rowp = (const float4*)(apre + (size_t)r * NLAT);
  unsigned dm = 0;
#pragma unroll
  for (int i = 0; i < GRP; ++i) {
    int g = t + SELT * i;
    float4 v = rowp[g];
    key[4 * i + 0] = fkey(v.x); key[4 * i + 1] = fkey(v.y);
    key[4 * i + 2] = fkey(v.z); key[4 * i + 3] = fkey(v.w);
    unsigned nb = (dbits[g >> 3] >> ((g & 7) * 4)) & 0xFu;
    dm |= nb << (4 * i);
  }
  int kmain = kptr[0]; if (kmain > MAIN_CAP) kmain = MAIN_CAP;
  int kaux  = akptr[0]; if (kaux > AUX_CAP)  kaux  = AUX_CAP;

  int par = 0, paru = 0;
  int kcMain = 0, acAux = 0;

  for (int pass = 0; pass < 2; ++pass) {
    int kreq, nelig;
    if (pass == 0) { kreq = kmain; nelig = NLAT; }
    else {
      // marker 0u (< any finite key) for non-dead latents
#pragma unroll
      for (int e = 0; e < EPT; ++e)
        if (!((dm >> e) & 1u)) key[e] = 0u;
      int pc = __popc(dm & 0xFFFFFFu);
#pragma unroll
      for (int o = 32; o; o >>= 1) pc += __shfl_xor(pc, o);
      if (lane == 0) wred[par][wave] = pc;
      __syncthreads();
      nelig = 0;
#pragma unroll
      for (int w = 0; w < 16; ++w) nelig += wred[par][w];
      par ^= 1;
      kreq = kaux;
    }
    if (kreq > nelig) kreq = nelig;
    if (kreq <= 0) { if (pass == 1) acAux = 0; continue; }

    // ---- block max/min of eligible keys ----
    unsigned mx = 0u, mn = 0xFFFFFFFFu;
#pragma unroll
    for (int e = 0; e < EPT; ++e) {
      unsigned kk = key[e];
      bool el = (pass == 0) || ((dm >> e) & 1u);
      if (el) { mx = kk > mx ? kk : mx; mn = kk < mn ? kk : mn; }
    }
#pragma unroll
    for (int o = 32; o; o >>= 1) {
      unsigned om = __shfl_xor(mx, o); mx = om > mx ? om : mx;
      unsigned on = __shfl_xor(mn, o); mn = on < mn ? on : mn;
    }
    if (lane == 0) { wredu[paru][wave] = mx; wredu[paru ^ 1][wave] = mn; }
    __syncthreads();
    mx = 0u; mn = 0xFFFFFFFFu;
#pragma unroll
    for (int w = 0; w < 16; ++w) {
      unsigned a = wredu[paru][w], b = wredu[paru ^ 1][w];
      mx = a > mx ? a : mx; mn = b < mn ? b : mn;
    }
    __syncthreads();

    // ---- value-space 3-threshold probe for the k-th boundary window ----
    unsigned Tlo = mn, Thi = mx + 1u;
    int cLo = nelig, cHi = 0;
    float vlo = keyinv(mn), vhi = keyinv(mx);
    for (int it = 0; it < 24 && (cLo - cHi) > (CAND_CAP - 8); ++it) {
      float v1 = 0.75f * vlo + 0.25f * vhi;
      float v2 = 0.50f * vlo + 0.50f * vhi;
      float v3 = 0.25f * vlo + 0.75f * vhi;
      unsigned T1 = fkey(v1), T2 = fkey(v2), T3 = fkey(v3);
      if (!(T1 > Tlo && T3 < Thi && T1 <= T2 && T2 <= T3)) break;
      int c1 = 0, c2 = 0, c3 = 0;
#pragma unroll
      for (int e = 0; e < EPT; ++e) {
        unsigned kk = key[e];
        c1 += (kk >= T1) ? 1 : 0;
        c2 += (kk >= T2) ? 1 : 0;
        c3 += (kk >= T3) ? 1 : 0;
      }
#pragma unroll
      for (int o = 32; o; o >>= 1) {
        c1 += __shfl_xor(c1, o); c2 += __shfl_xor(c2, o); c3 += __shfl_xor(c3, o);
      }
      if (lane == 0) {
        wred[par][wave * 3 + 0] = c1;
        wred[par][wave * 3 + 1] = c2;
        wred[par][wave * 3 + 2] = c3;
      }
      __syncthreads();
      c1 = 0; c2 = 0; c3 = 0;
#pragma unroll
      for (int w = 0; w < 16; ++w) {
        c1 += wred[par][w * 3 + 0];
        c2 += wred[par][w * 3 + 1];
        c3 += wred[par][w * 3 + 2];
      }
      par ^= 1;
      // counts descending: c1 >= c2 >= c3
      if (c3 >= kreq)      { Tlo = T3; cLo = c3; vlo = v3; }
      else if (c2 >= kreq) { Tlo = T2; cLo = c2; vlo = v2; Thi = T3; cHi = c3; vhi = v3; }
      else if (c1 >= kreq) { Tlo = T1; cLo = c1; vlo = v1; Thi = T2; cHi = c2; vhi = v2; }
      else                 { Thi = T1; cHi = c1; vhi = v1; }
    }

    // ---- extract window candidates, exact-rank the k-th key ----
    if (t == 0) ctrl[0] = 0;
    __syncthreads();
#pragma unroll
    for (int i = 0; i < GRP; ++i)
#pragma unroll
      for (int q = 0; q < 4; ++q) {
        unsigned kk = key[4 * i + q];
        if (kk >= Tlo && kk < Thi) {
          int p = atomicAdd(&ctrl[0], 1);
          if (p < CAND_CAP) { candK[p] = kk; candI[p] = 4 * (t + SELT * i) + q; }
        }
      }
    __syncthreads();
    int cc = ctrl[0]; if (cc > CAND_CAP) cc = CAND_CAP;
    int need = kreq - cHi;
    if (need < 1) need = 1;
    if (need > cc) need = cc;
    if (t < cc) {
      unsigned ki = candK[t]; int ii = candI[t];
      int rank = 0;
      for (int qq = 0; qq < cc; ++qq) {
        unsigned kq = candK[qq];
        rank += (kq > ki || (kq == ki && candI[qq] < ii)) ? 1 : 0;
      }
      if (rank == need - 1) ctrl[1] = (int)ki;
    }
    __syncthreads();

    // ---- f64 band refinement around V* ----
    float Vs = keyinv((unsigned)ctrl[1]);
    float eps = 1e-2f + 2e-3f * fabsf(Vs);
    unsigned KhiB = fkey(Vs + eps), KloB = fkey(Vs - eps);
    if (t == 0) { ctrl[2] = 0; ctrl[3] = 0; }
    __syncthreads();
    int abv = 0;
#pragma unroll
    for (int i = 0; i < GRP; ++i)
#pragma unroll
      for (int q = 0; q < 4; ++q) {
        unsigned kk = key[4 * i + q];
        if (kk > KhiB) ++abv;
        else if (kk >= KloB) {
          int p = atomicAdd(&ctrl[3], 1);
          if (p < BAND_CAP) bandI[p] = 4 * (t + SELT * i) + q;
        }
      }
#pragma unroll
    for (int o = 32; o; o >>= 1) abv += __shfl_xor(abv, o);
    if (lane == 0) atomicAdd(&ctrl[2], abv);
    __syncthreads();
    int nAb = ctrl[2];
    int bc = ctrl[3]; if (bc > BAND_CAP) bc = BAND_CAP;
    int needB = kreq - nAb;
    if (needB < 0) needB = 0;
    if (needB > bc) needB = bc;

    // wave-per-member f64 dot: lane l covers cols l, l+64, ... (coalesced)
    {
      const float* xr = x + (size_t)r * NIN;
      for (int m = wave; m < bc; m += 16) {
        int j = bandI[m];
        const float* wr = We + (size_t)j * NIN;
        double s = 0.0;
#pragma unroll
        for (int jj = 0; jj < NIN / 64; ++jj) {
          int col = lane + 64 * jj;
          s += ((double)xr[col] - (double)bvec[col]) * (double)wr[col];
        }
#pragma unroll
        for (int o = 32; o; o >>= 1) s += __shfl_xor(s, o);
        if (lane == 0) bandV[m] = s + (double)be[j];
      }
    }
    __syncthreads();
    if (t < bc) {
      double vi = bandV[t]; int ii = bandI[t];
      double tie = fabs(vi) * 4e-8 + 1e-12;
      int rank = 0;
      for (int qq = 0; qq < bc; ++qq) {
        double d = bandV[qq] - vi;
        rank += ((fabs(d) <= tie) ? (bandI[qq] < ii) : (d > 0.0)) ? 1 : 0;
      }
      bandSel[t] = (rank < needB) ? 1 : 0;
    }
    if (t == 0) ctrl[4] = 0;
    __syncthreads();

    // ---- emit ----
    if (pass == 0) {
      float4* arow = (float4*)(alpha + (size_t)r * NLAT);
      float4* mrow = (float4*)(mask + (size_t)r * NLAT);
#pragma unroll
      for (int i = 0; i < GRP; ++i) {
        float av[4], mv[4];
#pragma unroll
        for (int q = 0; q < 4; ++q) {
          unsigned kk = key[4 * i + q];
          int j = 4 * (t + SELT * i) + q;
          bool sel = kk > KhiB;
          if (!sel && kk >= KloB) {
            for (int m2 = 0; m2 < bc; ++m2)
              if (bandI[m2] == j) { sel = bandSel[m2] != 0; break; }
          }
          float v = keyinv(kk);
          bool nz = sel && (v != 0.0f);
          av[q] = sel ? v : 0.0f;
          mv[q] = nz ? 1.0f : 0.0f;
          if (nz) {
            int p = atomicAdd(&ctrl[4], 1);
            if (p < MAIN_CAP) { mIdx[p] = j; mVal[p] = v; }
          }
        }
        arow[t + SELT * i] = make_float4(av[0], av[1], av[2], av[3]);
        mrow[t + SELT * i] = make_float4(mv[0], mv[1], mv[2], mv[3]);
      }
    } else {
#pragma unroll
      for (int i = 0; i < GRP; ++i)
#pragma unroll
        for (int q = 0; q < 4; ++q) {
          unsigned kk = key[4 * i + q];
          if (kk == 0u) continue;  // marker (non-dead)
          int j = 4 * (t + SELT * i) + q;
          bool sel = kk > KhiB;
          if (!sel && kk >= KloB) {
            for (int m2 = 0; m2 < bc; ++m2)
              if (bandI[m2] == j) { sel = bandSel[m2] != 0; break; }
          }
          float v = keyinv(kk);
          if (sel && v != 0.0f) {
            int p = atomicAdd(&ctrl[4], 1);
            if (p < AUX_CAP) { aIdx[p] = j; aVal[p] = v; }
          }
        }
    }
    __syncthreads();
    if (pass == 0) kcMain = ctrl[4] < MAIN_CAP ? ctrl[4] : MAIN_CAP;
    else           acAux  = ctrl[4] < AUX_CAP  ? ctrl[4] : AUX_CAP;
    __syncthreads();
  }

  // ---- decode (threads 0..767), chunk-8 prefetch to overlap gather latency ----
  if (t < NIN) {
    int kc = kcMain, ac = acAux;
    float o0 = 0.f, o1 = 0.f, a0 = 0.f, a1 = 0.f;
    if (Wt) {
      int i = 0;
      for (; i + 8 <= kc; i += 8) {
        int ix[8]; float vv[8]; float w[8];
#pragma unroll
        for (int u = 0; u < 8; ++u) { ix[u] = mIdx[i + u]; vv[u] = mVal[i + u]; }
#pragma unroll
        for (int u = 0; u < 8; ++u) w[u] = (float)Wt[(size_t)ix[u] * NIN + t];
#pragma unroll
        for (int u = 0; u < 8; ++u) {
          if (u & 1) o1 = fmaf(vv[u], w[u], o1); else o0 = fmaf(vv[u], w[u], o0);
        }
      }
      for (; i < kc; ++i) o0 = fmaf(mVal[i], (float)Wt[(size_t)mIdx[i] * NIN + t], o0);
      i = 0;
      for (; i + 8 <= ac; i += 8) {
        int ix[8]; float vv[8]; float w[8];
#pragma unroll
        for (int u = 0; u < 8; ++u) { ix[u] = aIdx[i + u]; vv[u] = aVal[i + u]; }
#pragma unroll
        for (int u = 0; u < 8; ++u) w[u] = (float)Wt[(size_t)ix[u] * NIN + t];
#pragma unroll
        for (int u = 0; u < 8; ++u) {
          if (u & 1) a1 = fmaf(vv[u], w[u], a1); else a0 = fmaf(vv[u], w[u], a0);
        }
      }
      for (; i < ac; ++i) a0 = fmaf(aVal[i], (float)Wt[(size_t)aIdx[i] * NIN + t], a0);
    } else {
      int i = 0;
      for (; i + 8 <= ac; i += 8) {
        int ix[8]; float vv[8]; float w[8];
#pragma unroll
        for (int u = 0; u < 8; ++u) { ix[u] = aIdx[i + u]; vv[u] = aVal[i + u]; }
#pragma unroll
        for (int u = 0; u < 8; ++u) w[u] = Wd[(size_t)t * NLAT + ix[u]];
#pragma unroll
        for (int u = 0; u < 8; ++u) {
          if (u & 1) a1 = fmaf(vv[u], w[u], a1); else a0 = fmaf(vv[u], w[u], a0);
        }
      }
      for (; i < ac; ++i) a0 = fmaf(aVal[i], Wd[(size_t)t * NLAT + aIdx[i]], a0);
      for (i = 0; i < kc; ++i) o0 = fmaf(mVal[i], Wd[(size_t)t * NLAT + mIdx[i]], o0);
    }
    float bb = bvec[t];
    xhat[(size_t)r * NIN + t] = (o0 + o1) + bb;
    auxo[(size_t)r * NIN + t] = (a0 + a1) + bb;
  }
}

extern "C" void kernel_launch(void* const* d_in, const int* in_sizes, int n_in,
                              void* d_out, int out_size, void* d_ws, size_t ws_size,
                              hipStream_t stream) {
  const float* x  = (const float*)d_in[0];
  const float* bv = (const float*)d_in[1];
  const float* We = (const float*)d_in[2];
  const float* be = (const float*)d_in[3];
  const float* Wd = (const float*)d_in[4];
  const int* miss = (const int*)d_in[5];
  const int* kp   = (const int*)d_in[6];
  const int* akp  = (const int*)d_in[7];

  float* out   = (float*)d_out;
  float* xhat  = out;                          // [4096 x 768]
  float* alpha = out + (size_t)3145728;        // [4096 x 24576]
  float* apre  = out + (size_t)103809024;      // fired_mask region; alpha_pre scratch
  float* auxo  = out + (size_t)204472320;      // [4096 x 768]

  // ws layout: deadbits (64K pad) | Wt bf16 (36M) | A2 (12M) | B2 (72M)
  unsigned* dbits = (unsigned*)d_ws;
  size_t offWt = 65536;
  size_t offA2 = offWt + (size_t)NLAT * NIN * 2;
  size_t offB2 = offA2 + (size_t)NB * K2 * 2;
  size_t needFull = offB2 + (size_t)NLAT * K2 * 2;
  bool haveWt   = ws_size >= offA2;
  bool haveFull = ws_size >= needFull;
  __bf16* Wt = haveWt ? (__bf16*)((char*)d_ws + offWt) : nullptr;
  __bf16* A2 = (__bf16*)((char*)d_ws + offA2);
  __bf16* B2 = (__bf16*)((char*)d_ws + offB2);

  k_deadbits<<<96, 256, 0, stream>>>(miss, dbits);
  if (haveFull) {
    k_pack_a<<<dim3(32, KT2), 256, 0, stream>>>(x, bv, A2);
    k_pack_b<<<dim3(192, KT2), 256, 0, stream>>>(We, B2);
  }
  if (haveWt)
    k_transpose<<<dim3(NLAT / 32, NIN / 32), dim3(32, 8), 0, stream>>>(Wd, Wt);

  if (haveFull)
    k_gemm_bf16<<<dim3(32, 192), 256, 0, stream>>>(A2, B2, be, apre);
  else
    k_encgemm_f32<<<dim3(NB / BM, NLAT / BN), 256, 0, stream>>>(x, bv, We, be, apre);

  k_select4<<<NB, SELT, 0, stream>>>(apre, x, bv, We, be, dbits, kp, akp,
                                     alpha, apre, xhat, auxo, Wt, Wd);
}

// Round 6
// 7838.863 us; speedup vs baseline: 2.6372x; 2.6372x over previous
//
#include <hip/hip_runtime.h>
#include <math.h>

#define NB   4096
#define NIN  768
#define NLAT 24576
#define K2   1536   // [Ah|Al] x [Bh|Bh]
#define KT2  24     // K2/64

// f32 fallback GEMM tiling
#define BM 128
#define BN 128
#define BK 16
#define LDT 132

#define CAND_CAP 160
#define BAND_CAP 160
#define MAIN_CAP 64
#define AUX_CAP  1024
#define SELT     1024
#define EPT      24     // elements per thread = NLAT/SELT
#define GRP      6      // float4 groups per thread

typedef __bf16 bf16x8 __attribute__((ext_vector_type(8)));
typedef float  f32x4  __attribute__((ext_vector_type(4)));

__device__ __forceinline__ unsigned fkey(float f) {
  unsigned u = __float_as_uint(f);
  return u ^ ((unsigned)((int)u >> 31) | 0x80000000u);  // monotone total order
}
__device__ __forceinline__ float keyinv(unsigned u) {
  unsigned s = (u & 0x80000000u) ? (u ^ 0x80000000u) : ~u;
  return __uint_as_float(s);
}

#define GLOAD16(g, l) __builtin_amdgcn_global_load_lds( \
    (const __attribute__((address_space(1))) unsigned int*)(g), \
    (__attribute__((address_space(3))) unsigned int*)(l), 16, 0, 0)

// ---------------- dead bitset: bit j = (miss[j] >= 1) ----------------
__global__ __launch_bounds__(256) void k_deadbits(const int* __restrict__ miss,
                                                  unsigned* __restrict__ bits) {
  int j = blockIdx.x * 256 + threadIdx.x;
  unsigned long long b = __ballot(miss[j] >= 1);
  if ((threadIdx.x & 63) == 0) {
    int w = j >> 5;
    bits[w] = (unsigned)b;
    bits[w + 1] = (unsigned)(b >> 32);
  }
}

// ---------------- W_dec [NIN][NLAT] -> Wt [NLAT][NIN] (bf16) ----------------
__global__ __launch_bounds__(256) void k_transpose(const float* __restrict__ src,
                                                   __bf16* __restrict__ dst) {
  __shared__ float tile[32][33];
  int bx = blockIdx.x * 32;  // NLAT
  int by = blockIdx.y * 32;  // NIN
  int tx = threadIdx.x, ty = threadIdx.y;
  for (int i = ty; i < 32; i += 8)
    tile[i][tx] = src[(size_t)(by + i) * NLAT + bx + tx];
  __syncthreads();
  for (int i = ty; i < 32; i += 8)
    dst[(size_t)(bx + i) * NIN + by + tx] = (__bf16)tile[tx][i];
}

// ---- pack (x-b) into A2 tiles [mt][kt][128][64], pre-swizzled LDS image ----
__global__ __launch_bounds__(256) void k_pack_a(const float* __restrict__ x,
    const float* __restrict__ bvec, __bf16* __restrict__ A2) {
  const int mt = blockIdx.x, kt = blockIdx.y, t = threadIdx.x;
  __bf16* out = A2 + (((size_t)mt * KT2 + kt) << 13);
#pragma unroll
  for (int i = 0; i < 32; ++i) {
    int idx = i * 256 + t;
    int r = idx >> 6, c2 = idx & 63;
    int kk = c2 ^ ((r & 7) << 3);
    int kg = kt * 64 + kk;
    int k = kg >= 768 ? kg - 768 : kg;
    bool lo = (kg >= 768);                            // A = [Ah | Al]
    float v = x[(size_t)(mt * 128 + r) * NIN + k] - bvec[k];
    __bf16 h = (__bf16)v;
    out[idx] = lo ? (__bf16)(v - (float)h) : h;
  }
}

__global__ __launch_bounds__(256) void k_pack_b(const float* __restrict__ We,
    __bf16* __restrict__ B2) {
  const int nt = blockIdx.x, kt = blockIdx.y, t = threadIdx.x;
  __bf16* out = B2 + (((size_t)nt * KT2 + kt) << 13);
#pragma unroll
  for (int i = 0; i < 32; ++i) {
    int idx = i * 256 + t;
    int r = idx >> 6, c2 = idx & 63;
    int kk = c2 ^ ((r & 7) << 3);
    int kg = kt * 64 + kk;
    int k = kg >= 768 ? kg - 768 : kg;                // B = [Bh | Bh]
    float v = We[(size_t)(nt * 128 + r) * NIN + k];
    out[idx] = (__bf16)v;
  }
}

// ---------------- bf16 MFMA GEMM: apre = A2 @ B2^T + be ----------------
__global__ __launch_bounds__(256) void k_gemm_bf16(
    const __bf16* __restrict__ A2, const __bf16* __restrict__ B2,
    const float* __restrict__ be, float* __restrict__ apre) {
  __shared__ char sA[16384];
  __shared__ char sB[16384];
  const int t = threadIdx.x;
  const int lane = t & 63, wave = t >> 6;
  const int mt = blockIdx.x, nt = blockIdx.y;
  const int wm = wave >> 1, wn = wave & 1;

  int aoff[4][2], boff[4][2];
#pragma unroll
  for (int f = 0; f < 4; ++f) {
    int ra = wm * 64 + f * 16 + (lane & 15);
    int rb = wn * 64 + f * 16 + (lane & 15);
#pragma unroll
    for (int kk = 0; kk < 2; ++kk) {
      int c = kk * 64 + (lane >> 4) * 16;
      aoff[f][kk] = ra * 128 + (c ^ ((ra & 7) << 4));
      boff[f][kk] = rb * 128 + (c ^ ((rb & 7) << 4));
    }
  }
  f32x4 acc[4][4] = {};
  const char* gA = (const char*)(A2 + (((size_t)mt * KT2) << 13));
  const char* gB = (const char*)(B2 + (((size_t)nt * KT2) << 13));
  for (int kt = 0; kt < KT2; ++kt) {
    const char* tA = gA + ((size_t)kt << 14);
    const char* tB = gB + ((size_t)kt << 14);
#pragma unroll
    for (int i = 0; i < 4; ++i) {
      int chunk = (i * 4 + wave) * 1024;
      GLOAD16(tA + chunk + lane * 16, sA + chunk);
      GLOAD16(tB + chunk + lane * 16, sB + chunk);
    }
    __syncthreads();
#pragma unroll
    for (int kk = 0; kk < 2; ++kk) {
      bf16x8 a[4], b[4];
#pragma unroll
      for (int f = 0; f < 4; ++f) {
        a[f] = *(const bf16x8*)(sA + aoff[f][kk]);
        b[f] = *(const bf16x8*)(sB + boff[f][kk]);
      }
#pragma unroll
      for (int mi = 0; mi < 4; ++mi)
#pragma unroll
        for (int ni = 0; ni < 4; ++ni)
          acc[mi][ni] = __builtin_amdgcn_mfma_f32_16x16x32_bf16(a[mi], b[ni], acc[mi][ni], 0, 0, 0);
    }
    __syncthreads();
  }
  const int m0 = mt * 128 + wm * 64, n0 = nt * 128 + wn * 64;
#pragma unroll
  for (int ni = 0; ni < 4; ++ni) {
    int n = n0 + ni * 16 + (lane & 15);
    float bb = be[n];
#pragma unroll
    for (int mi = 0; mi < 4; ++mi) {
      int mbase = m0 + mi * 16 + (lane >> 4) * 4;
#pragma unroll
      for (int q = 0; q < 4; ++q)
        apre[(size_t)(mbase + q) * NLAT + n] = acc[mi][ni][q] + bb;
    }
  }
}

// ---------------- f32 fallback GEMM ----------------
__global__ __launch_bounds__(256) void k_encgemm_f32(
    const float* __restrict__ x, const float* __restrict__ bvec,
    const float* __restrict__ We, const float* __restrict__ be,
    float* __restrict__ apre) {
  __shared__ float As[BK][LDT];
  __shared__ float Bs[BK][LDT];
  const int t = threadIdx.x;
  const int m0 = blockIdx.x * BM;
  const int n0 = blockIdx.y * BN;
  const int lane = t & 63, wave = t >> 6;
  const int cn = ((wave & 1) * 8 + (lane & 7)) * 8;
  const int cm = ((wave >> 1) * 8 + (lane >> 3)) * 8;
  float acc[8][8] = {};
  const float* xb = x + (size_t)m0 * NIN;
  const float* wb = We + (size_t)n0 * NIN;
  for (int k0 = 0; k0 < NIN; k0 += BK) {
#pragma unroll
    for (int i = 0; i < 2; ++i) {
      int e = t + i * 256;
      int row = e >> 2, q = e & 3;
      float4 bv = *(const float4*)(bvec + k0 + q * 4);
      float4 av = *(const float4*)(xb + (size_t)row * NIN + k0 + q * 4);
      av.x -= bv.x; av.y -= bv.y; av.z -= bv.z; av.w -= bv.w;
      As[q * 4 + 0][row] = av.x; As[q * 4 + 1][row] = av.y;
      As[q * 4 + 2][row] = av.z; As[q * 4 + 3][row] = av.w;
      float4 wv = *(const float4*)(wb + (size_t)row * NIN + k0 + q * 4);
      Bs[q * 4 + 0][row] = wv.x; Bs[q * 4 + 1][row] = wv.y;
      Bs[q * 4 + 2][row] = wv.z; Bs[q * 4 + 3][row] = wv.w;
    }
    __syncthreads();
#pragma unroll
    for (int kk = 0; kk < BK; ++kk) {
      float a0[8], b0[8];
      *(float4*)&a0[0] = *(const float4*)&As[kk][cm];
      *(float4*)&a0[4] = *(const float4*)&As[kk][cm + 4];
      *(float4*)&b0[0] = *(const float4*)&Bs[kk][cn];
      *(float4*)&b0[4] = *(const float4*)&Bs[kk][cn + 4];
#pragma unroll
      for (int i = 0; i < 8; ++i)
#pragma unroll
        for (int j = 0; j < 8; ++j)
          acc[i][j] = fmaf(a0[i], b0[j], acc[i][j]);
    }
    __syncthreads();
  }
  float bb[8];
  *(float4*)&bb[0] = *(const float4*)(be + n0 + cn);
  *(float4*)&bb[4] = *(const float4*)(be + n0 + cn + 4);
#pragma unroll
  for (int i = 0; i < 8; ++i) {
    float4 v0 = make_float4(acc[i][0] + bb[0], acc[i][1] + bb[1],
                            acc[i][2] + bb[2], acc[i][3] + bb[3]);
    float4 v1 = make_float4(acc[i][4] + bb[4], acc[i][5] + bb[5],
                            acc[i][6] + bb[6], acc[i][7] + bb[7]);
    float* orow = apre + (size_t)(m0 + cm + i) * NLAT + n0 + cn;
    *(float4*)orow = v0;
    *(float4*)(orow + 4) = v1;
  }
}

// ------------- per-row: 1024-thread register-resident top-k select ----
// apre and mask alias — no __restrict__ on either; each block owns its row.
__global__ __launch_bounds__(SELT) void k_select5(
    const float* apre, const float* __restrict__ x,
    const float* __restrict__ bvec, const float* __restrict__ We,
    const float* __restrict__ be, const unsigned* __restrict__ dbits,
    const int* __restrict__ kptr, const int* __restrict__ akptr,
    float* __restrict__ alpha, float* mask,
    int* __restrict__ cnts, int* __restrict__ mIdxG, float* __restrict__ mValG,
    int* __restrict__ aIdxG, float* __restrict__ aValG) {
  const int t = threadIdx.x;
  const int r = blockIdx.x;
  const int lane = t & 63, wave = t >> 6;   // 16 waves

  __shared__ int wred[2][48];
  __shared__ unsigned wredu[2][16];
  __shared__ int ctrl[8];
  __shared__ unsigned candK[CAND_CAP];
  __shared__ int candI[CAND_CAP];
  __shared__ int bandI[BAND_CAP];
  __shared__ double bandV[BAND_CAP];
  __shared__ unsigned char bandSel[BAND_CAP];

  // ---- load row as sort keys (24 regs) + dead bits (1 reg) ----
  unsigned key[EPT];
  const float4* rowp = (const float4*)(apre + (size_t)r * NLAT);
  unsigned dm = 0;
#pragma unroll
  for (int i = 0; i < GRP; ++i) {
    int g = t + SELT * i;
    float4 v = rowp[g];
    key[4 * i + 0] = fkey(v.x); key[4 * i + 1] = fkey(v.y);
    key[4 * i + 2] = fkey(v.z); key[4 * i + 3] = fkey(v.w);
    unsigned nb = (dbits[g >> 3] >> ((g & 7) * 4)) & 0xFu;
    dm |= nb << (4 * i);
  }
  int kmain = kptr[0]; if (kmain > MAIN_CAP) kmain = MAIN_CAP;
  int kaux  = akptr[0]; if (kaux > AUX_CAP)  kaux  = AUX_CAP;

  int par = 0, paru = 0;

  for (int pass = 0; pass < 2; ++pass) {
    int kreq, nelig;
    if (pass == 0) { kreq = kmain; nelig = NLAT; }
    else {
      // marker 0u (< any finite key) for non-dead latents
#pragma unroll
      for (int e = 0; e < EPT; ++e)
        if (!((dm >> e) & 1u)) key[e] = 0u;
      int pc = __popc(dm & 0xFFFFFFu);
#pragma unroll
      for (int o = 32; o; o >>= 1) pc += __shfl_xor(pc, o);
      if (lane == 0) wred[par][wave] = pc;
      __syncthreads();
      nelig = 0;
#pragma unroll
      for (int w = 0; w < 16; ++w) nelig += wred[par][w];
      par ^= 1;
      kreq = kaux;
    }
    if (kreq > nelig) kreq = nelig;
    if (kreq <= 0) {
      if (t == 0) cnts[2 * r + pass] = 0;
      continue;
    }

    // ---- block max/min of eligible keys ----
    unsigned mx = 0u, mn = 0xFFFFFFFFu;
#pragma unroll
    for (int e = 0; e < EPT; ++e) {
      unsigned kk = key[e];
      bool el = (pass == 0) || ((dm >> e) & 1u);
      if (el) { mx = kk > mx ? kk : mx; mn = kk < mn ? kk : mn; }
    }
#pragma unroll
    for (int o = 32; o; o >>= 1) {
      unsigned om = __shfl_xor(mx, o); mx = om > mx ? om : mx;
      unsigned on = __shfl_xor(mn, o); mn = on < mn ? on : mn;
    }
    if (lane == 0) { wredu[paru][wave] = mx; wredu[paru ^ 1][wave] = mn; }
    __syncthreads();
    mx = 0u; mn = 0xFFFFFFFFu;
#pragma unroll
    for (int w = 0; w < 16; ++w) {
      unsigned a = wredu[paru][w], b = wredu[paru ^ 1][w];
      mx = a > mx ? a : mx; mn = b < mn ? b : mn;
    }
    __syncthreads();

    // ---- value-space 3-threshold probe for the k-th boundary window ----
    unsigned Tlo = mn, Thi = mx + 1u;
    int cLo = nelig, cHi = 0;
    float vlo = keyinv(mn), vhi = keyinv(mx);
    for (int it = 0; it < 24 && (cLo - cHi) > (CAND_CAP - 8); ++it) {
      float v1 = 0.75f * vlo + 0.25f * vhi;
      float v2 = 0.50f * vlo + 0.50f * vhi;
      float v3 = 0.25f * vlo + 0.75f * vhi;
      unsigned T1 = fkey(v1), T2 = fkey(v2), T3 = fkey(v3);
      if (!(T1 > Tlo && T3 < Thi && T1 <= T2 && T2 <= T3)) break;
      int c1 = 0, c2 = 0, c3 = 0;
#pragma unroll
      for (int e = 0; e < EPT; ++e) {
        unsigned kk = key[e];
        c1 += (kk >= T1) ? 1 : 0;
        c2 += (kk >= T2) ? 1 : 0;
        c3 += (kk >= T3) ? 1 : 0;
      }
#pragma unroll
      for (int o = 32; o; o >>= 1) {
        c1 += __shfl_xor(c1, o); c2 += __shfl_xor(c2, o); c3 += __shfl_xor(c3, o);
      }
      if (lane == 0) {
        wred[par][wave * 3 + 0] = c1;
        wred[par][wave * 3 + 1] = c2;
        wred[par][wave * 3 + 2] = c3;
      }
      __syncthreads();
      c1 = 0; c2 = 0; c3 = 0;
#pragma unroll
      for (int w = 0; w < 16; ++w) {
        c1 += wred[par][w * 3 + 0];
        c2 += wred[par][w * 3 + 1];
        c3 += wred[par][w * 3 + 2];
      }
      par ^= 1;
      // counts descending: c1 >= c2 >= c3
      if (c3 >= kreq)      { Tlo = T3; cLo = c3; vlo = v3; }
      else if (c2 >= kreq) { Tlo = T2; cLo = c2; vlo = v2; Thi = T3; cHi = c3; vhi = v3; }
      else if (c1 >= kreq) { Tlo = T1; cLo = c1; vlo = v1; Thi = T2; cHi = c2; vhi = v2; }
      else                 { Thi = T1; cHi = c1; vhi = v1; }
    }

    // ---- extract window candidates, exact-rank the k-th key ----
    if (t == 0) ctrl[0] = 0;
    __syncthreads();
#pragma unroll
    for (int i = 0; i < GRP; ++i)
#pragma unroll
      for (int q = 0; q < 4; ++q) {
        unsigned kk = key[4 * i + q];
        if (kk >= Tlo && kk < Thi) {
          int p = atomicAdd(&ctrl[0], 1);
          if (p < CAND_CAP) { candK[p] = kk; candI[p] = 4 * (t + SELT * i) + q; }
        }
      }
    __syncthreads();
    int cc = ctrl[0]; if (cc > CAND_CAP) cc = CAND_CAP;
    int need = kreq - cHi;
    if (need < 1) need = 1;
    if (need > cc) need = cc;
    if (t < cc) {
      unsigned ki = candK[t]; int ii = candI[t];
      int rank = 0;
      for (int qq = 0; qq < cc; ++qq) {
        unsigned kq = candK[qq];
        rank += (kq > ki || (kq == ki && candI[qq] < ii)) ? 1 : 0;
      }
      if (rank == need - 1) ctrl[1] = (int)ki;
    }
    __syncthreads();

    // ---- f64 band refinement around V* ----
    float Vs = keyinv((unsigned)ctrl[1]);
    float eps = 1e-2f + 2e-3f * fabsf(Vs);
    unsigned KhiB = fkey(Vs + eps), KloB = fkey(Vs - eps);
    if (t == 0) { ctrl[2] = 0; ctrl[3] = 0; }
    __syncthreads();
    int abv = 0;
#pragma unroll
    for (int i = 0; i < GRP; ++i)
#pragma unroll
      for (int q = 0; q < 4; ++q) {
        unsigned kk = key[4 * i + q];
        if (kk > KhiB) ++abv;
        else if (kk >= KloB) {
          int p = atomicAdd(&ctrl[3], 1);
          if (p < BAND_CAP) bandI[p] = 4 * (t + SELT * i) + q;
        }
      }
#pragma unroll
    for (int o = 32; o; o >>= 1) abv += __shfl_xor(abv, o);
    if (lane == 0) atomicAdd(&ctrl[2], abv);
    __syncthreads();
    int nAb = ctrl[2];
    int bc = ctrl[3]; if (bc > BAND_CAP) bc = BAND_CAP;
    int needB = kreq - nAb;
    if (needB < 0) needB = 0;
    if (needB > bc) needB = bc;

    // wave-per-member f64 dot: lane l covers cols l, l+64, ... (coalesced)
    {
      const float* xr = x + (size_t)r * NIN;
      for (int m = wave; m < bc; m += 16) {
        int j = bandI[m];
        const float* wr = We + (size_t)j * NIN;
        double s = 0.0;
#pragma unroll
        for (int jj = 0; jj < NIN / 64; ++jj) {
          int col = lane + 64 * jj;
          s += ((double)xr[col] - (double)bvec[col]) * (double)wr[col];
        }
#pragma unroll
        for (int o = 32; o; o >>= 1) s += __shfl_xor(s, o);
        if (lane == 0) bandV[m] = s + (double)be[j];
      }
    }
    __syncthreads();
    if (t < bc) {
      double vi = bandV[t]; int ii = bandI[t];
      double tie = fabs(vi) * 4e-8 + 1e-12;
      int rank = 0;
      for (int qq = 0; qq < bc; ++qq) {
        double d = bandV[qq] - vi;
        rank += ((fabs(d) <= tie) ? (bandI[qq] < ii) : (d > 0.0)) ? 1 : 0;
      }
      bandSel[t] = (rank < needB) ? 1 : 0;
    }
    if (t == 0) ctrl[4] = 0;
    __syncthreads();

    // ---- emit ----
    if (pass == 0) {
      float4* arow = (float4*)(alpha + (size_t)r * NLAT);
      float4* mrow = (float4*)(mask + (size_t)r * NLAT);
#pragma unroll
      for (int i = 0; i < GRP; ++i) {
        float av[4], mv[4];
#pragma unroll
        for (int q = 0; q < 4; ++q) {
          unsigned kk = key[4 * i + q];
          int j = 4 * (t + SELT * i) + q;
          bool sel = kk > KhiB;
          if (!sel && kk >= KloB) {
            for (int m2 = 0; m2 < bc; ++m2)
              if (bandI[m2] == j) { sel = bandSel[m2] != 0; break; }
          }
          float v = keyinv(kk);
          bool nz = sel && (v != 0.0f);
          av[q] = sel ? v : 0.0f;
          mv[q] = nz ? 1.0f : 0.0f;
          if (nz) {
            int p = atomicAdd(&ctrl[4], 1);
            if (p < MAIN_CAP) { mIdxG[r * MAIN_CAP + p] = j; mValG[r * MAIN_CAP + p] = v; }
          }
        }
        arow[t + SELT * i] = make_float4(av[0], av[1], av[2], av[3]);
        mrow[t + SELT * i] = make_float4(mv[0], mv[1], mv[2], mv[3]);
      }
    } else {
#pragma unroll
      for (int i = 0; i < GRP; ++i)
#pragma unroll
        for (int q = 0; q < 4; ++q) {
          unsigned kk = key[4 * i + q];
          if (kk == 0u) continue;  // marker (non-dead)
          int j = 4 * (t + SELT * i) + q;
          bool sel = kk > KhiB;
          if (!sel && kk >= KloB) {
            for (int m2 = 0; m2 < bc; ++m2)
              if (bandI[m2] == j) { sel = bandSel[m2] != 0; break; }
          }
          float v = keyinv(kk);
          if (sel && v != 0.0f) {
            int p = atomicAdd(&ctrl[4], 1);
            if (p < AUX_CAP) { aIdxG[r * AUX_CAP + p] = j; aValG[r * AUX_CAP + p] = v; }
          }
        }
    }
    __syncthreads();
    if (t == 0) {
      int c = ctrl[4];
      int cap = (pass == 0) ? MAIN_CAP : AUX_CAP;
      cnts[2 * r + pass] = c < cap ? c : cap;
    }
    __syncthreads();
  }
}

// ------------- decode: xhat/auxo from (idx,val) lists; no VGPR cap ----
__global__ __launch_bounds__(256) void k_decode(
    const int* __restrict__ cnts, const int* __restrict__ mIdxG,
    const float* __restrict__ mValG, const int* __restrict__ aIdxG,
    const float* __restrict__ aValG, const float* __restrict__ bvec,
    const __bf16* __restrict__ Wt, const float* __restrict__ Wd,
    float* __restrict__ xhat, float* __restrict__ auxo) {
  const int r = blockIdx.x, t = threadIdx.x;
  __shared__ int sMi[MAIN_CAP];
  __shared__ float sMv[MAIN_CAP];
  __shared__ int sAi[AUX_CAP];
  __shared__ float sAv[AUX_CAP];
  int kc = cnts[2 * r], ac = cnts[2 * r + 1];
  if (t < MAIN_CAP && t < kc) { sMi[t] = mIdxG[r * MAIN_CAP + t]; sMv[t] = mValG[r * MAIN_CAP + t]; }
  for (int i = t; i < ac; i += 256) { sAi[i] = aIdxG[r * AUX_CAP + i]; sAv[i] = aValG[r * AUX_CAP + i]; }
  __syncthreads();

  float o0 = 0.f, o1 = 0.f, o2 = 0.f;   // cols t, t+256, t+512
  float a0 = 0.f, a1 = 0.f, a2 = 0.f;
  if (Wt) {
    int i = 0;
    for (; i + 4 <= kc; i += 4) {
      int i0 = sMi[i], i1 = sMi[i + 1], i2 = sMi[i + 2], i3 = sMi[i + 3];
      float v0 = sMv[i], v1 = sMv[i + 1], v2 = sMv[i + 2], v3 = sMv[i + 3];
      const __bf16* p0 = Wt + (size_t)i0 * NIN;
      const __bf16* p1 = Wt + (size_t)i1 * NIN;
      const __bf16* p2 = Wt + (size_t)i2 * NIN;
      const __bf16* p3 = Wt + (size_t)i3 * NIN;
      float w00 = p0[t], w01 = p0[t + 256], w02 = p0[t + 512];
      float w10 = p1[t], w11 = p1[t + 256], w12 = p1[t + 512];
      float w20 = p2[t], w21 = p2[t + 256], w22 = p2[t + 512];
      float w30 = p3[t], w31 = p3[t + 256], w32 = p3[t + 512];
      o0 = fmaf(v0, w00, o0); o1 = fmaf(v0, w01, o1); o2 = fmaf(v0, w02, o2);
      o0 = fmaf(v1, w10, o0); o1 = fmaf(v1, w11, o1); o2 = fmaf(v1, w12, o2);
      o0 = fmaf(v2, w20, o0); o1 = fmaf(v2, w21, o1); o2 = fmaf(v2, w22, o2);
      o0 = fmaf(v3, w30, o0); o1 = fmaf(v3, w31, o1); o2 = fmaf(v3, w32, o2);
    }
    for (; i < kc; ++i) {
      const __bf16* p = Wt + (size_t)sMi[i] * NIN;
      float v = sMv[i];
      o0 = fmaf(v, (float)p[t], o0);
      o1 = fmaf(v, (float)p[t + 256], o1);
      o2 = fmaf(v, (float)p[t + 512], o2);
    }
    i = 0;
    for (; i + 4 <= ac; i += 4) {
      int i0 = sAi[i], i1 = sAi[i + 1], i2 = sAi[i + 2], i3 = sAi[i + 3];
      float v0 = sAv[i], v1 = sAv[i + 1], v2 = sAv[i + 2], v3 = sAv[i + 3];
      const __bf16* p0 = Wt + (size_t)i0 * NIN;
      const __bf16* p1 = Wt + (size_t)i1 * NIN;
      const __bf16* p2 = Wt + (size_t)i2 * NIN;
      const __bf16* p3 = Wt + (size_t)i3 * NIN;
      float w00 = p0[t], w01 = p0[t + 256], w02 = p0[t + 512];
      float w10 = p1[t], w11 = p1[t + 256], w12 = p1[t + 512];
      float w20 = p2[t], w21 = p2[t + 256], w22 = p2[t + 512];
      float w30 = p3[t], w31 = p3[t + 256], w32 = p3[t + 512];
      a0 = fmaf(v0, w00, a0); a1 = fmaf(v0, w01, a1); a2 = fmaf(v0, w02, a2);
      a0 = fmaf(v1, w10, a0); a1 = fmaf(v1, w11, a1); a2 = fmaf(v1, w12, a2);
      a0 = fmaf(v2, w20, a0); a1 = fmaf(v2, w21, a1); a2 = fmaf(v2, w22, a2);
      a0 = fmaf(v3, w30, a0); a1 = fmaf(v3, w31, a1); a2 = fmaf(v3, w32, a2);
    }
    for (; i < ac; ++i) {
      const __bf16* p = Wt + (size_t)sAi[i] * NIN;
      float v = sAv[i];
      a0 = fmaf(v, (float)p[t], a0);
      a1 = fmaf(v, (float)p[t + 256], a1);
      a2 = fmaf(v, (float)p[t + 512], a2);
    }
  } else {  // fallback: strided gather from W_dec [NIN][NLAT]
    for (int i = 0; i < kc; ++i) {
      float v = sMv[i]; int ix = sMi[i];
      o0 = fmaf(v, Wd[(size_t)t * NLAT + ix], o0);
      o1 = fmaf(v, Wd[(size_t)(t + 256) * NLAT + ix], o1);
      o2 = fmaf(v, Wd[(size_t)(t + 512) * NLAT + ix], o2);
    }
    for (int i = 0; i < ac; ++i) {
      float v = sAv[i]; int ix = sAi[i];
      a0 = fmaf(v, Wd[(size_t)t * NLAT + ix], a0);
      a1 = fmaf(v, Wd[(size_t)(t + 256) * NLAT + ix], a1);
      a2 = fmaf(v, Wd[(size_t)(t + 512) * NLAT + ix], a2);
    }
  }
  float b0 = bvec[t], b1 = bvec[t + 256], b2 = bvec[t + 512];
  xhat[(size_t)r * NIN + t] = o0 + b0;
  xhat[(size_t)r * NIN + t + 256] = o1 + b1;
  xhat[(size_t)r * NIN + t + 512] = o2 + b2;
  auxo[(size_t)r * NIN + t] = a0 + b0;
  auxo[(size_t)r * NIN + t + 256] = a1 + b1;
  auxo[(size_t)r * NIN + t + 512] = a2 + b2;
}

extern "C" void kernel_launch(void* const* d_in, const int* in_sizes, int n_in,
                              void* d_out, int out_size, void* d_ws, size_t ws_size,
                              hipStream_t stream) {
  const float* x  = (const float*)d_in[0];
  const float* bv = (const float*)d_in[1];
  const float* We = (const float*)d_in[2];
  const float* be = (const float*)d_in[3];
  const float* Wd = (const float*)d_in[4];
  const int* miss = (const int*)d_in[5];
  const int* kp   = (const int*)d_in[6];
  const int* akp  = (const int*)d_in[7];

  float* out   = (float*)d_out;
  float* xhat  = out;                          // [4096 x 768]
  float* alpha = out + (size_t)3145728;        // [4096 x 24576]
  float* apre  = out + (size_t)103809024;      // fired_mask region; alpha_pre scratch
  float* auxo  = out + (size_t)204472320;      // [4096 x 768]

  // ws layout: dbits 64K | cnts 64K | mIdx 1M | mVal 1M | aIdx 16M | aVal 16M
  //            | Wt bf16 36M | A2 12M | B2 72M   (~154 MB total)
  char* wsb = (char*)d_ws;
  unsigned* dbits = (unsigned*)wsb;
  int*   cnts  = (int*)(wsb + 65536);
  int*   mIdxG = (int*)(wsb + 131072);
  float* mValG = (float*)(wsb + 131072 + (size_t)NB * MAIN_CAP * 4);
  int*   aIdxG = (int*)(wsb + 131072 + (size_t)NB * MAIN_CAP * 8);
  float* aValG = (float*)(wsb + 131072 + (size_t)NB * MAIN_CAP * 8 + (size_t)NB * AUX_CAP * 4);
  size_t offWt = 131072 + (size_t)NB * MAIN_CAP * 8 + (size_t)NB * AUX_CAP * 8;
  size_t offA2 = offWt + (size_t)NLAT * NIN * 2;
  size_t offB2 = offA2 + (size_t)NB * K2 * 2;
  size_t needFull = offB2 + (size_t)NLAT * K2 * 2;
  bool haveWt   = ws_size >= offA2;
  bool haveFull = ws_size >= needFull;
  __bf16* Wt = haveWt ? (__bf16*)(wsb + offWt) : nullptr;
  __bf16* A2 = (__bf16*)(wsb + offA2);
  __bf16* B2 = (__bf16*)(wsb + offB2);

  k_deadbits<<<96, 256, 0, stream>>>(miss, dbits);
  if (haveFull) {
    k_pack_a<<<dim3(32, KT2), 256, 0, stream>>>(x, bv, A2);
    k_pack_b<<<dim3(192, KT2), 256, 0, stream>>>(We, B2);
  }
  if (haveWt)
    k_transpose<<<dim3(NLAT / 32, NIN / 32), dim3(32, 8), 0, stream>>>(Wd, Wt);

  if (haveFull)
    k_gemm_bf16<<<dim3(32, 192), 256, 0, stream>>>(A2, B2, be, apre);
  else
    k_encgemm_f32<<<dim3(NB / BM, NLAT / BN), 256, 0, stream>>>(x, bv, We, be, apre);

  k_select5<<<NB, SELT, 0, stream>>>(apre, x, bv, We, be, dbits, kp, akp,
                                     alpha, apre, cnts, mIdxG, mValG, aIdxG, aValG);
  k_decode<<<NB, 256, 0, stream>>>(cnts, mIdxG, mValG, aIdxG, aValG, bv,
                                   Wt, Wd, xhat, auxo);
}